// Round 3
// baseline (47.897 us; speedup 1.0000x reference)
//
#include <hip/hip_runtime.h>

#define BB 8
#define DD 65536
#define GG 1024
#define OUTN 4096
#define NBLK (DD / 64)   // 1024 blocks, 64 threads each

// Fused: partial dot per block + last-block finalize (deterministic fixed-order
// reduction; only WHICH block finalizes varies, not the values).
__global__ __launch_bounds__(64) void ril_fused(
    const float* __restrict__ x,        // (8, 65536)
    const float* __restrict__ weights,  // (1024*65536,)
    const float* __restrict__ min_vals, // (1024,)
    const float* __restrict__ max_vals, // (1024,)
    const int* __restrict__ start_pos,  // (1024,)
    const int* __restrict__ offsets,    // (1024,)
    const int* __restrict__ sizes,      // (1024,)
    const int* __restrict__ out_mask,   // (4096,) bool pushed as int32
    float* __restrict__ out,            // (8*4096,)
    float* __restrict__ partials,       // d_ws: 1024 floats
    unsigned int* __restrict__ counter, // d_ws + 4096 (memset to 0 each call)
    int wlen)
{
    const int t   = threadIdx.x;
    const int bid = blockIdx.x;
    const int d   = bid * 64 + t;

    // Issue all 8 x-row loads immediately (independent, coalesced).
    float x0 = x[0 * DD + d];
    float x1 = x[1 * DD + d];
    float x2 = x[2 * DD + d];
    float x3 = x[3 * DD + d];
    float x4 = x[4 * DD + d];
    float x5 = x[5 * DD + d];
    float x6 = x[6 * DD + d];
    float x7 = x[7 * DD + d];

    const float m0    = min_vals[0];
    const float mlast = min_vals[GG - 1];

    const float v = (((x0 + x1) + (x2 + x3)) + ((x4 + x5) + (x6 + x7))) * 0.125f;

    // Analytic guess for g = searchsorted(min_vals, v, 'right') - 1, exact fixup.
    float inv = (mlast > m0) ? (float)(GG - 1) / (mlast - m0) : 0.0f;
    float gf = (v - m0) * inv;
    gf = fminf(fmaxf(gf, -1.0f), (float)(GG - 1));
    int gi = (int)floorf(gf);
    while (gi + 1 < GG && min_vals[gi + 1] <= v) ++gi;
    while (gi >= 0 && min_vals[gi] > v) --gi;

    const int g  = gi;
    const int gc = min(max(g, 0), GG - 1);

    const float mn = min_vals[gc];
    const float mx = max_vals[gc];
    const int   sp = start_pos[gc];
    const int   of = offsets[gc];
    const int   sz = sizes[gc];

    const bool in_range = (g >= 0) && (v >= mn) && (v <= mx);
    const int  pos      = d - sp;
    const bool valid    = in_range && (pos >= 0) && (pos < sz);

    int widx = of + pos;
    widx = min(max(widx, 0), wlen - 1);
    const float w = valid ? weights[widx] : 0.0f;

    float p = v * w;

    // wave64 shuffle reduce (fixed order -> deterministic)
#pragma unroll
    for (int off = 32; off > 0; off >>= 1) p += __shfl_down(p, off);

    // Publish partial (release, device scope), then signal.
    unsigned int old = 0;
    if (t == 0) {
        __hip_atomic_store(&partials[bid], p, __ATOMIC_RELEASE, __HIP_MEMORY_SCOPE_AGENT);
        old = __hip_atomic_fetch_add(counter, 1u, __ATOMIC_ACQ_REL, __HIP_MEMORY_SCOPE_AGENT);
    }
    // Broadcast "am I the finalizer" to the wave.
    old = __shfl(old, 0);

    // Rows 1..7 are constant zeros: blocks 0..111 write them after signaling
    // (112 blocks * 64 threads * float4 = 28672 floats).
    if (bid < (BB - 1) * OUTN / 256) {
        const int q = OUTN + (bid * 64 + t) * 4;
        *reinterpret_cast<float4*>(&out[q]) = float4{0.0f, 0.0f, 0.0f, 0.0f};
    }

    if (old == NBLK - 1) {
        // Last block: fixed-order reduce of all partials, then write row 0.
        float acc = 0.0f;
#pragma unroll
        for (int i = 0; i < NBLK / 64; ++i) {
            acc += __hip_atomic_load(&partials[t + i * 64], __ATOMIC_ACQUIRE,
                                     __HIP_MEMORY_SCOPE_AGENT);
        }
#pragma unroll
        for (int off = 32; off > 0; off >>= 1) acc += __shfl_down(acc, off);
        const float s = __shfl(acc, 0);

        // Row 0: 4096 floats = 64 threads * 16 float4 stores.
#pragma unroll
        for (int j = 0; j < OUTN / 256; ++j) {
            const int q = (j * 64 + t) * 4;
            const int4 m = *reinterpret_cast<const int4*>(&out_mask[q]);
            float4 val;
            val.x = m.x ? s : 0.0f;
            val.y = m.y ? s : 0.0f;
            val.z = m.z ? s : 0.0f;
            val.w = m.w ? s : 0.0f;
            *reinterpret_cast<float4*>(&out[q]) = val;
        }
    }
}

extern "C" void kernel_launch(void* const* d_in, const int* in_sizes, int n_in,
                              void* d_out, int out_size, void* d_ws, size_t ws_size,
                              hipStream_t stream) {
    const float* x        = (const float*)d_in[0];
    const float* weights  = (const float*)d_in[1];
    const float* min_vals = (const float*)d_in[2];
    const float* max_vals = (const float*)d_in[3];
    const int*   start_p  = (const int*)d_in[4];
    const int*   offsets  = (const int*)d_in[5];
    const int*   sizes    = (const int*)d_in[6];
    const int*   out_mask = (const int*)d_in[7];
    float* out = (float*)d_out;

    float*        partials = (float*)d_ws;                        // 4 KB
    unsigned int* counter  = (unsigned int*)((char*)d_ws + 4096); // 4 B

    const int wlen = in_sizes[1];

    // Counter must be 0 at kernel start on EVERY call (ws is poisoned to 0xAA).
    hipMemsetAsync(counter, 0, sizeof(unsigned int), stream);

    ril_fused<<<NBLK, 64, 0, stream>>>(
        x, weights, min_vals, max_vals, start_p, offsets, sizes, out_mask,
        out, partials, counter, wlen);
}

// Round 4
// 42.264 us; speedup vs baseline: 1.1333x; 1.1333x over previous
//
#include <hip/hip_runtime.h>

#define BB 8
#define DD 65536
#define GG 1024
#define OUTN 4096
#define NBLK (DD / 64)   // 1024 blocks, 64 threads each

// Fused: partial dot per block + last-block finalize.
// Deterministic: reduction order is fixed; only WHICH block finalizes varies.
// Coherence design (the R3 lesson): exactly ONE acquire (the acq_rel fetch_add,
// whose RMW chain synchronizes with all 1023 prior release stores). Partial
// reads are RELAXED agent-scope loads -> coherent reads via L3, NO per-load
// cache invalidation.
__global__ __launch_bounds__(64) void ril_fused(
    const float* __restrict__ x,        // (8, 65536)
    const float* __restrict__ weights,  // (1024*65536,)
    const float* __restrict__ min_vals, // (1024,)
    const float* __restrict__ max_vals, // (1024,)
    const int* __restrict__ start_pos,  // (1024,)
    const int* __restrict__ offsets,    // (1024,)
    const int* __restrict__ sizes,      // (1024,)
    const int* __restrict__ out_mask,   // (4096,) bool pushed as int32
    float* __restrict__ out,            // (8*4096,)
    float* __restrict__ partials,       // d_ws: 1024 floats
    unsigned int* __restrict__ counter, // d_ws + 4096 (memset to 0 each call)
    int wlen)
{
    const int t   = threadIdx.x;
    const int bid = blockIdx.x;
    const int d   = bid * 64 + t;

    // Issue all 8 x-row loads immediately (independent, coalesced).
    float x0 = x[0 * DD + d];
    float x1 = x[1 * DD + d];
    float x2 = x[2 * DD + d];
    float x3 = x[3 * DD + d];
    float x4 = x[4 * DD + d];
    float x5 = x[5 * DD + d];
    float x6 = x[6 * DD + d];
    float x7 = x[7 * DD + d];

    const float m0    = min_vals[0];
    const float mlast = min_vals[GG - 1];

    const float v = (((x0 + x1) + (x2 + x3)) + ((x4 + x5) + (x6 + x7))) * 0.125f;

    // Analytic guess for g = searchsorted(min_vals, v, 'right') - 1, exact fixup.
    float inv = (mlast > m0) ? (float)(GG - 1) / (mlast - m0) : 0.0f;
    float gf = (v - m0) * inv;
    gf = fminf(fmaxf(gf, -1.0f), (float)(GG - 1));
    int gi = (int)floorf(gf);
    while (gi + 1 < GG && min_vals[gi + 1] <= v) ++gi;
    while (gi >= 0 && min_vals[gi] > v) --gi;

    const int g  = gi;
    const int gc = min(max(g, 0), GG - 1);

    const float mn = min_vals[gc];
    const float mx = max_vals[gc];
    const int   sp = start_pos[gc];
    const int   of = offsets[gc];
    const int   sz = sizes[gc];

    const bool in_range = (g >= 0) && (v >= mn) && (v <= mx);
    const int  pos      = d - sp;
    const bool valid    = in_range && (pos >= 0) && (pos < sz);

    int widx = of + pos;
    widx = min(max(widx, 0), wlen - 1);
    const float w = valid ? weights[widx] : 0.0f;

    float p = v * w;

    // wave64 shuffle reduce (fixed order -> deterministic)
#pragma unroll
    for (int off = 32; off > 0; off >>= 1) p += __shfl_down(p, off);

    // Publish partial (release), then signal (the ONLY acquire lives here).
    unsigned int old = 0;
    if (t == 0) {
        __hip_atomic_store(&partials[bid], p, __ATOMIC_RELEASE, __HIP_MEMORY_SCOPE_AGENT);
        old = __hip_atomic_fetch_add(counter, 1u, __ATOMIC_ACQ_REL, __HIP_MEMORY_SCOPE_AGENT);
    }
    old = __shfl(old, 0);

    // Rows 1..7 are constant zeros: blocks 0..111 write them after signaling
    // (112 blocks * 64 threads * float4 = 28672 floats).
    if (bid < (BB - 1) * OUTN / 256) {
        const int q = OUTN + (bid * 64 + t) * 4;
        *reinterpret_cast<float4*>(&out[q]) = float4{0.0f, 0.0f, 0.0f, 0.0f};
    }

    if (old == NBLK - 1) {
        // Last block: RELAXED coherent loads (no invalidates), fixed-order sum.
        float vals[NBLK / 64];
#pragma unroll
        for (int i = 0; i < NBLK / 64; ++i) {
            vals[i] = __hip_atomic_load(&partials[t + i * 64], __ATOMIC_RELAXED,
                                        __HIP_MEMORY_SCOPE_AGENT);
        }
        float acc = 0.0f;
#pragma unroll
        for (int i = 0; i < NBLK / 64; ++i) acc += vals[i];
#pragma unroll
        for (int off = 32; off > 0; off >>= 1) acc += __shfl_down(acc, off);
        const float s = __shfl(acc, 0);

        // Row 0: 4096 floats = 64 threads * 16 float4 stores.
#pragma unroll
        for (int j = 0; j < OUTN / 256; ++j) {
            const int q = (j * 64 + t) * 4;
            const int4 m = *reinterpret_cast<const int4*>(&out_mask[q]);
            float4 val;
            val.x = m.x ? s : 0.0f;
            val.y = m.y ? s : 0.0f;
            val.z = m.z ? s : 0.0f;
            val.w = m.w ? s : 0.0f;
            *reinterpret_cast<float4*>(&out[q]) = val;
        }
    }
}

extern "C" void kernel_launch(void* const* d_in, const int* in_sizes, int n_in,
                              void* d_out, int out_size, void* d_ws, size_t ws_size,
                              hipStream_t stream) {
    const float* x        = (const float*)d_in[0];
    const float* weights  = (const float*)d_in[1];
    const float* min_vals = (const float*)d_in[2];
    const float* max_vals = (const float*)d_in[3];
    const int*   start_p  = (const int*)d_in[4];
    const int*   offsets  = (const int*)d_in[5];
    const int*   sizes    = (const int*)d_in[6];
    const int*   out_mask = (const int*)d_in[7];
    float* out = (float*)d_out;

    float*        partials = (float*)d_ws;                        // 4 KB
    unsigned int* counter  = (unsigned int*)((char*)d_ws + 4096); // 4 B

    const int wlen = in_sizes[1];

    // Counter must be 0 at kernel start on EVERY call (ws is poisoned to 0xAA).
    hipMemsetAsync(counter, 0, sizeof(unsigned int), stream);

    ril_fused<<<NBLK, 64, 0, stream>>>(
        x, weights, min_vals, max_vals, start_p, offsets, sizes, out_mask,
        out, partials, counter, wlen);
}

// Round 5
// 17.076 us; speedup vs baseline: 2.8049x; 2.4751x over previous
//
#include <hip/hip_runtime.h>

#define BB 8
#define DD 65536
#define GG 1024
#define OUTN 4096
#define TPB 1024
#define NB (DD / TPB)   // 64 blocks, 1024 threads each, 1 element per thread

// Fused single-kernel: per-block partial dot + last-block finalize.
// Coherence design (R3/R4 lessons):
//  - per-block signal is a RELEASE-only fetch_add  -> NO per-block buffer_inv
//  - exactly ONE acquire fence, in the finalizer   -> one invalidate total
//  - partial reads are RELAXED agent-scope loads   -> read-through, no inv
// Deterministic: all reduction orders fixed; only WHICH block finalizes varies.
__global__ __launch_bounds__(TPB) void ril_fused(
    const float* __restrict__ x,        // (8, 65536)
    const float* __restrict__ weights,  // (1024*65536,)
    const float* __restrict__ min_vals, // (1024,)
    const float* __restrict__ max_vals, // (1024,)
    const int* __restrict__ start_pos,  // (1024,)
    const int* __restrict__ offsets,    // (1024,)
    const int* __restrict__ sizes,      // (1024,)
    const int* __restrict__ out_mask,   // (4096,) bool pushed as int32
    float* __restrict__ out,            // (8*4096,)
    float* __restrict__ partials,       // d_ws: 64 floats
    unsigned int* __restrict__ counter, // d_ws + 4096 (memset to 0 each call)
    int wlen)
{
    const int t   = threadIdx.x;
    const int bid = blockIdx.x;
    const int d   = bid * TPB + t;

    // Issue all 8 x-row loads immediately (independent, coalesced).
    float x0 = x[0 * DD + d];
    float x1 = x[1 * DD + d];
    float x2 = x[2 * DD + d];
    float x3 = x[3 * DD + d];
    float x4 = x[4 * DD + d];
    float x5 = x[5 * DD + d];
    float x6 = x[6 * DD + d];
    float x7 = x[7 * DD + d];

    const float m0    = min_vals[0];
    const float mlast = min_vals[GG - 1];

    const float v = (((x0 + x1) + (x2 + x3)) + ((x4 + x5) + (x6 + x7))) * 0.125f;

    // Analytic guess for g = searchsorted(min_vals, v, 'right') - 1, exact fixup.
    float inv = (mlast > m0) ? (float)(GG - 1) / (mlast - m0) : 0.0f;
    float gf = (v - m0) * inv;
    gf = fminf(fmaxf(gf, -1.0f), (float)(GG - 1));
    int gi = (int)floorf(gf);
    while (gi + 1 < GG && min_vals[gi + 1] <= v) ++gi;
    while (gi >= 0 && min_vals[gi] > v) --gi;

    const int g  = gi;
    const int gc = min(max(g, 0), GG - 1);

    const float mn = min_vals[gc];
    const float mx = max_vals[gc];
    const int   sp = start_pos[gc];
    const int   of = offsets[gc];
    const int   sz = sizes[gc];

    const bool in_range = (g >= 0) && (v >= mn) && (v <= mx);
    const int  pos      = d - sp;
    const bool valid    = in_range && (pos >= 0) && (pos < sz);

    int widx = of + pos;
    widx = min(max(widx, 0), wlen - 1);
    const float w = valid ? weights[widx] : 0.0f;

    float p = v * w;

    // wave64 shuffle reduce (fixed order -> deterministic)
#pragma unroll
    for (int off = 32; off > 0; off >>= 1) p += __shfl_down(p, off);

    __shared__ float s_wsum[TPB / 64];
    __shared__ unsigned int s_old;
    __shared__ float s_bcast;
    if ((t & 63) == 0) s_wsum[t >> 6] = p;

    // Rows 1..7 are constant zeros: blocks 1..7 write row `bid` while waiting.
    if (bid >= 1 && bid < BB) {
        *reinterpret_cast<float4*>(&out[bid * OUTN + t * 4]) =
            float4{0.0f, 0.0f, 0.0f, 0.0f};
    }
    __syncthreads();

    if (t == 0) {
        float q = 0.0f;
#pragma unroll
        for (int i = 0; i < TPB / 64; ++i) q += s_wsum[i];
        __hip_atomic_store(&partials[bid], q, __ATOMIC_RELEASE, __HIP_MEMORY_SCOPE_AGENT);
        // RELEASE-only signal: no invalidate on the 63 non-final blocks.
        s_old = __hip_atomic_fetch_add(counter, 1u, __ATOMIC_RELEASE, __HIP_MEMORY_SCOPE_AGENT);
    }
    __syncthreads();

    if (s_old == NB - 1) {
        // The ONE acquire in the kernel: makes all release-stored partials visible.
        __builtin_amdgcn_fence(__ATOMIC_ACQUIRE, "agent");

        float val = 0.0f;
        if (t < NB) {
            val = __hip_atomic_load(&partials[t], __ATOMIC_RELAXED,
                                    __HIP_MEMORY_SCOPE_AGENT);
        }
        if (t < 64) {
#pragma unroll
            for (int off = 32; off > 0; off >>= 1) val += __shfl_down(val, off);
            if (t == 0) s_bcast = val;
        }
        __syncthreads();
        const float s = s_bcast;

        // Row 0: 4096 floats = 1024 threads * one float4 each.
        const int q4 = t * 4;
        const int4 m = *reinterpret_cast<const int4*>(&out_mask[q4]);
        float4 val4;
        val4.x = m.x ? s : 0.0f;
        val4.y = m.y ? s : 0.0f;
        val4.z = m.z ? s : 0.0f;
        val4.w = m.w ? s : 0.0f;
        *reinterpret_cast<float4*>(&out[q4]) = val4;
    }
}

extern "C" void kernel_launch(void* const* d_in, const int* in_sizes, int n_in,
                              void* d_out, int out_size, void* d_ws, size_t ws_size,
                              hipStream_t stream) {
    const float* x        = (const float*)d_in[0];
    const float* weights  = (const float*)d_in[1];
    const float* min_vals = (const float*)d_in[2];
    const float* max_vals = (const float*)d_in[3];
    const int*   start_p  = (const int*)d_in[4];
    const int*   offsets  = (const int*)d_in[5];
    const int*   sizes    = (const int*)d_in[6];
    const int*   out_mask = (const int*)d_in[7];
    float* out = (float*)d_out;

    float*        partials = (float*)d_ws;                        // 64 floats
    unsigned int* counter  = (unsigned int*)((char*)d_ws + 4096); // 4 B

    const int wlen = in_sizes[1];

    // Counter must be 0 at kernel start on EVERY call (ws is poisoned to 0xAA).
    hipMemsetAsync(counter, 0, sizeof(unsigned int), stream);

    ril_fused<<<NB, TPB, 0, stream>>>(
        x, weights, min_vals, max_vals, start_p, offsets, sizes, out_mask,
        out, partials, counter, wlen);
}

// Round 6
// 11.164 us; speedup vs baseline: 4.2902x; 1.5295x over previous
//
#include <hip/hip_runtime.h>

#define BB 8
#define DD 65536
#define GG 1024
#define OUTN 4096

// Two-kernel form: kernel boundary is the only synchronization (no atomics,
// no fences -> no cross-XCD coherence traffic). Measured floor 11.08-11.10 us
// across structurally different variants => dispatch/replay-overhead-bound.

// ---------------- Kernel A: one wave per 64 d's, no LDS, no barrier ----------------
__global__ __launch_bounds__(64) void ril_partials(
    const float* __restrict__ x,        // (8, 65536)
    const float* __restrict__ weights,  // (1024*65536,)
    const float* __restrict__ min_vals, // (1024,)
    const float* __restrict__ max_vals, // (1024,)
    const int* __restrict__ start_pos,  // (1024,)
    const int* __restrict__ offsets,    // (1024,)
    const int* __restrict__ sizes,      // (1024,)
    float* __restrict__ partials,       // (1024,)
    int wlen)
{
    const int t = threadIdx.x;
    const int d = blockIdx.x * 64 + t;

    // Issue all 8 x-row loads immediately (independent, coalesced).
    float x0 = x[0 * DD + d];
    float x1 = x[1 * DD + d];
    float x2 = x[2 * DD + d];
    float x3 = x[3 * DD + d];
    float x4 = x[4 * DD + d];
    float x5 = x[5 * DD + d];
    float x6 = x[6 * DD + d];
    float x7 = x[7 * DD + d];

    const float m0    = min_vals[0];
    const float mlast = min_vals[GG - 1];

    const float v = (((x0 + x1) + (x2 + x3)) + ((x4 + x5) + (x6 + x7))) * 0.125f;

    // Analytic guess for g = searchsorted(min_vals, v, 'right') - 1,
    // then EXACT fixup (preserves reference semantics for any min_vals).
    float inv = (mlast > m0) ? (float)(GG - 1) / (mlast - m0) : 0.0f;
    float gf = (v - m0) * inv;
    gf = fminf(fmaxf(gf, -1.0f), (float)(GG - 1));
    int gi = (int)floorf(gf);
    while (gi + 1 < GG && min_vals[gi + 1] <= v) ++gi;
    while (gi >= 0 && min_vals[gi] > v) --gi;

    const int g  = gi;
    const int gc = min(max(g, 0), GG - 1);

    const float mn = min_vals[gc];
    const float mx = max_vals[gc];
    const int   sp = start_pos[gc];
    const int   of = offsets[gc];
    const int   sz = sizes[gc];

    const bool in_range = (g >= 0) && (v >= mn) && (v <= mx);
    const int  pos      = d - sp;
    const bool valid    = in_range && (pos >= 0) && (pos < sz);

    int widx = of + pos;
    widx = min(max(widx, 0), wlen - 1);
    const float w = valid ? weights[widx] : 0.0f;

    float p = v * w;

    // wave64 shuffle reduce (fixed order -> deterministic)
#pragma unroll
    for (int off = 32; off > 0; off >>= 1) p += __shfl_down(p, off);

    if (t == 0) partials[blockIdx.x] = p;
}

// ---------------- Kernel B: reduce 1024 partials, write output (float4) ----------------
__global__ __launch_bounds__(256) void ril_finalize(
    const float* __restrict__ partials, // (1024,)
    const int* __restrict__ out_mask,   // (4096,) bool pushed as int32
    float* __restrict__ out)            // (8*4096,)
{
    const int t = threadIdx.x;

    float p = (partials[t] + partials[t + 256]) + (partials[t + 512] + partials[t + 768]);
#pragma unroll
    for (int off = 32; off > 0; off >>= 1) p += __shfl_down(p, off);

    __shared__ float s_wsum[4];
    __shared__ float s_total;
    if ((t & 63) == 0) s_wsum[t >> 6] = p;
    __syncthreads();
    if (t == 0) s_total = (s_wsum[0] + s_wsum[1]) + (s_wsum[2] + s_wsum[3]);
    __syncthreads();
    const float s = s_total;

    // 32 blocks * 256 threads * 4 floats = 32768 outputs
    const int q = (blockIdx.x * 256 + t) * 4;
    float4 val = {0.0f, 0.0f, 0.0f, 0.0f};
    if (q < OUTN) {  // only row 0 (first 4096) can be nonzero
        const int4 m = *reinterpret_cast<const int4*>(&out_mask[q]);
        val.x = m.x ? s : 0.0f;
        val.y = m.y ? s : 0.0f;
        val.z = m.z ? s : 0.0f;
        val.w = m.w ? s : 0.0f;
    }
    *reinterpret_cast<float4*>(&out[q]) = val;
}

extern "C" void kernel_launch(void* const* d_in, const int* in_sizes, int n_in,
                              void* d_out, int out_size, void* d_ws, size_t ws_size,
                              hipStream_t stream) {
    const float* x        = (const float*)d_in[0];
    const float* weights  = (const float*)d_in[1];
    const float* min_vals = (const float*)d_in[2];
    const float* max_vals = (const float*)d_in[3];
    const int*   start_p  = (const int*)d_in[4];
    const int*   offsets  = (const int*)d_in[5];
    const int*   sizes    = (const int*)d_in[6];
    const int*   out_mask = (const int*)d_in[7];
    float* out = (float*)d_out;
    float* partials = (float*)d_ws;   // 1024 floats; every slot written each call

    const int wlen = in_sizes[1];

    ril_partials<<<DD / 64, 64, 0, stream>>>(
        x, weights, min_vals, max_vals, start_p, offsets, sizes, partials, wlen);

    ril_finalize<<<(BB * OUTN) / (256 * 4), 256, 0, stream>>>(partials, out_mask, out);
}